// Round 8
// baseline (397.526 us; speedup 1.0000x reference)
//
#include <hip/hip_runtime.h>
#include <math.h>
#include <stdint.h>

#define Bb   128
#define Nn   100
#define Ee   3200
#define NTOT (Bb*Nn)    // 12800
#define ETOT (Bb*Ee)    // 409600

// XCD swizzle: blockIdx&7 -> XCD (dispatch round-robin over 8 XCDs).
// Batch b lives on XCD b/16 across all kernels: producers and consumers of a
// batch's intermediates (cpair, z, k1, v1, a1) share an L2. Perf-only.
//
// Session law (R1/R3/R5/R6/R7): this workload is TLP-bound. Wide grids of
// small decoupled blocks win; any structure with few blocks + serial
// dependent chains loses (R7: fused per-batch attn = 90us vs ~40 split).
// Separate dispatches are the cheap sync primitive; grid.sync costs
// device-scope coherence (R6). 3 dispatches here.

__device__ __forceinline__ void ln_reg(float* h, const float* __restrict__ g,
                                       const float* __restrict__ b) {
    float s = 0.f;
#pragma unroll
    for (int c = 0; c < 16; c++) s += h[c];
    float m = s * 0.0625f;
    float v = 0.f;
#pragma unroll
    for (int c = 0; c < 16; c++) { float d = h[c] - m; v += d * d; }
    float r = rsqrtf(v * 0.0625f + 1e-5f);
#pragma unroll
    for (int c = 0; c < 16; c++) h[c] = (h[c] - m) * r * g[c] + b[c];
}

// ---------------- K_cmz: per-batch CSR + mark + edge-MLP + z/k/v ----------------
// Edges live in LDS for the CSR build -> run the MLP edge-centric right there:
// every lane owns a real edge (100% lane util vs wave-per-node's ~50%), no
// cpair re-read. h3 scatters into LDS z[100][17] via atomicAdd (pad 17 ->
// bank=(17d+c)&31 well spread; channel index compile-time). k/v per channel
// with weight rows hoisted to registers (all 64 lanes read zl[n][*] broadcast).

__global__ __launch_bounds__(512) void k_cmz(
    const int* __restrict__ ei, const int* __restrict__ agent,
    const float* __restrict__ nf, const float* __restrict__ ea, const float* __restrict__ ee,
    const float* __restrict__ W1, const float* __restrict__ b1,
    const float* __restrict__ W2, const float* __restrict__ b2,
    const float* __restrict__ W3, const float* __restrict__ b3,
    const float* __restrict__ lg, const float* __restrict__ lb,
    const float* __restrict__ Wk, const float* __restrict__ bk,
    const float* __restrict__ Wv, const float* __restrict__ bv,
    int* __restrict__ off, int2* __restrict__ cpair,
    int* __restrict__ mlist, int* __restrict__ mcnt,
    float* __restrict__ z, float* __restrict__ k1, float* __restrict__ v1)
{
    int b = ((blockIdx.x & 7) << 4) + (blockIdx.x >> 3);
    int t = threadIdx.x;
    __shared__ int   s_src[Ee];      // 12.8 KB
    __shared__ int   s_dst[Ee];      // 12.8 KB
    __shared__ float zl[Nn][17];     // 6.8 KB, pad 17 spreads banks
    __shared__ int   cnt[128], exc[128], cur[128];
    __shared__ int   smark[Nn], slist[Nn];
    __shared__ int   scnt;

    for (int i = t; i < Nn * 17; i += 512) ((float*)zl)[i] = 0.f;
    if (t < 128) cnt[t] = 0;
    if (t < Nn)  smark[t] = 0;
    if (t == 0)  scnt = 0;
    __syncthreads();

    // ---- load edges + degree count ----
    const int* eis = ei + (size_t)b * 2 * Ee;
    const int* eid = eis + Ee;
    for (int e = t; e < Ee; e += 512) {
        int s = eis[e];
        int d = eid[e];
        s_src[e] = s;
        s_dst[e] = d;
        atomicAdd(&cnt[d], 1);
    }
    __syncthreads();
    // ---- single-wave exclusive scan of cnt[128] ----
    if (t < 64) {
        int c0 = cnt[2 * t];
        int c1 = cnt[2 * t + 1];
        int p = c0 + c1;
#pragma unroll
        for (int d = 1; d < 64; d <<= 1) {
            int v = __shfl_up(p, d);
            if (t >= d) p += v;
        }
        exc[2 * t]     = p - c0 - c1;
        exc[2 * t + 1] = p - c1;
        cur[2 * t]     = p - c0 - c1;
        cur[2 * t + 1] = p - c1;
    }
    __syncthreads();
    if (t < Nn) off[b * Nn + t] = b * Ee + exc[t];
    if (b == Bb - 1 && t == 0) off[NTOT] = ETOT;
    // ---- CSR fill (for attn kernels) ----
    for (int e = t; e < Ee; e += 512) {
        int d = s_dst[e];
        int idx = atomicAdd(&cur[d], 1);
        cpair[b * Ee + idx] = make_int2(s_src[e] + b * Nn, b * Ee + e);
    }
    // ---- compact marked list ----
    int an = agent[b];
    if (t == 0) {
        int old = atomicExch(&smark[an], 1);
        if (!old) { int ix = atomicAdd(&scnt, 1); slist[ix] = an; }
    }
    for (int e = t; e < Ee; e += 512) {
        if (s_dst[e] == an) {
            int s = s_src[e];
            int old = atomicExch(&smark[s], 1);
            if (!old) { int ix = atomicAdd(&scnt, 1); slist[ix] = s; }
        }
    }
    // ---- edge-centric MLP, scatter h3 into zl ----
    for (int e = t; e < Ee; e += 512) {
        int src = s_src[e];
        int dst = s_dst[e];
        int et = (int)nf[b * Nn + src];
        float in[12];
#pragma unroll
        for (int j = 0; j < 4; j++) in[j] = ee[et * 4 + j];
        const float4* ea4 = (const float4*)(ea + ((size_t)b * Ee + e) * 8);
        float4 ua = ea4[0], ub = ea4[1];
        in[4] = ua.x; in[5] = ua.y; in[6] = ua.z; in[7] = ua.w;
        in[8] = ub.x; in[9] = ub.y; in[10] = ub.z; in[11] = ub.w;

        float h1[16];
#pragma unroll
        for (int c = 0; c < 16; c++) {
            float s = b1[c];
#pragma unroll
            for (int j = 0; j < 12; j++) s = fmaf(W1[c * 12 + j], in[j], s);
            h1[c] = fmaxf(s, 0.f);
        }
        ln_reg(h1, lg, lb);
        float h2[16];
#pragma unroll
        for (int c = 0; c < 16; c++) {
            float s = b2[c];
#pragma unroll
            for (int j = 0; j < 16; j++) s = fmaf(W2[c * 16 + j], h1[j], s);
            h2[c] = fmaxf(s, 0.f);
        }
        ln_reg(h2, lg, lb);
        float h3[16];
#pragma unroll
        for (int c = 0; c < 16; c++) {
            float s = b3[c];
#pragma unroll
            for (int j = 0; j < 16; j++) s = fmaf(W3[c * 16 + j], h2[j], s);
            h3[c] = fmaxf(s, 0.f);
        }
        ln_reg(h3, lg, lb);
#pragma unroll
        for (int c = 0; c < 16; c++) atomicAdd(&zl[dst][c], h3[c]);
    }
    __syncthreads();

    // ---- mlist/mcnt ----
    if (t < scnt) mlist[b * Nn + t] = slist[t];
    if (t == 0)   mcnt[b] = scnt;

    // ---- z, k1, v1: channel-per-lane, node striped over waves ----
    {
        int ch = t & 63;          // lane
        int n0 = t >> 6;          // wave id 0..7
        float wkr[16], wvr[16];
#pragma unroll
        for (int j = 0; j < 16; j++) { wkr[j] = Wk[ch * 16 + j]; wvr[j] = Wv[ch * 16 + j]; }
        float bkv = bk[ch], bvv = bv[ch];
        for (int n = n0; n < Nn; n += 8) {
            float zz[16];
#pragma unroll
            for (int j = 0; j < 16; j++) zz[j] = zl[n][j];   // broadcast: all lanes same row
            if (ch < 16) z[((size_t)b * Nn + n) * 16 + ch] = zl[n][ch];
            float ak = bkv, av = bvv;
#pragma unroll
            for (int j = 0; j < 16; j++) {
                ak = fmaf(wkr[j], zz[j], ak);
                av = fmaf(wvr[j], zz[j], av);
            }
            k1[((size_t)b * Nn + n) * 64 + ch] = ak;
            v1[((size_t)b * Nn + n) * 64 + ch] = av;
        }
    }
}

// ---------------- K_attn1: g1 attention, one block per marked node ----------------
// Compact list: grid 128x50, block handles marked idx {rep, rep+50} (mcnt<=100).
// 4 waves split the node's edges (contiguous quarters), online-softmax each,
// associative LDS merge. Gathers hit the producing XCD's L2 (no staging).

__global__ __launch_bounds__(256) void k_attn1(
    const float* __restrict__ ea,
    const float* __restrict__ k1, const float* __restrict__ v1,
    const float* __restrict__ z,
    const int* __restrict__ mlist, const int* __restrict__ mcnt,
    const float* __restrict__ Wq, const float* __restrict__ bq,
    const float* __restrict__ We, const float* __restrict__ Ws, const float* __restrict__ bs,
    const int* __restrict__ off, const int2* __restrict__ cpair,
    float* __restrict__ a1)
{
    __shared__ float sm[4][64], sl[4][64], sa[4][64];
    int bl   = blockIdx.x & 127;
    int rep  = blockIdx.x >> 7;               // 0..49
    int b    = ((bl & 7) << 4) + (bl >> 3);
    int lane = threadIdx.x & 63;
    int w    = threadIdx.x >> 6;
    int mc   = mcnt[b];

    float wq[16], wer[8];
#pragma unroll
    for (int j = 0; j < 16; j++) wq[j] = Wq[lane * 16 + j];
#pragma unroll
    for (int j = 0; j < 8; j++) wer[j] = We[lane * 8 + j];
    float bq1 = bq[lane];

    for (int ix = rep; ix < mc; ix += 50) {
        int n = b * Nn + mlist[b * Nn + ix];

        float zz[16];
#pragma unroll
        for (int j = 0; j < 16; j++) zz[j] = z[n * 16 + j];
        float ql = bq1;
#pragma unroll
        for (int j = 0; j < 16; j++) ql = fmaf(wq[j], zz[j], ql);

        int o0  = off[n];
        int deg = off[n + 1] - o0;
        int i    = o0 + ((deg * w) >> 2);       // contiguous quarter per wave
        int iend = o0 + ((deg * (w + 1)) >> 2);

        float m = -1e30f, l = 0.f, acc = 0.f;
        for (; i + 2 <= iend; i += 2) {
            int2 pA = cpair[i];
            int2 pB = cpair[i + 1];
            const float4* eaA = (const float4*)(ea + (size_t)pA.y * 8);
            const float4* eaB = (const float4*)(ea + (size_t)pB.y * 8);
            float4 a0v = eaA[0], a1v = eaA[1], b0v = eaB[0], b1v = eaB[1];
            float eA = wer[0] * a0v.x + wer[1] * a0v.y + wer[2] * a0v.z + wer[3] * a0v.w
                     + wer[4] * a1v.x + wer[5] * a1v.y + wer[6] * a1v.z + wer[7] * a1v.w;
            float eB = wer[0] * b0v.x + wer[1] * b0v.y + wer[2] * b0v.z + wer[3] * b0v.w
                     + wer[4] * b1v.x + wer[5] * b1v.y + wer[6] * b1v.z + wer[7] * b1v.w;
            float kA = k1[(size_t)pA.x * 64 + lane];
            float kB = k1[(size_t)pB.x * 64 + lane];
            float vA = v1[(size_t)pA.x * 64 + lane];
            float vB = v1[(size_t)pB.x * 64 + lane];
            float tA = ql * (kA + eA);
            float tB = ql * (kB + eB);
            tA += __shfl_xor(tA, 1, 16);  tB += __shfl_xor(tB, 1, 16);
            tA += __shfl_xor(tA, 2, 16);  tB += __shfl_xor(tB, 2, 16);
            tA += __shfl_xor(tA, 4, 16);  tB += __shfl_xor(tB, 4, 16);
            tA += __shfl_xor(tA, 8, 16);  tB += __shfl_xor(tB, 8, 16);
            float lA  = tA * 0.25f;
            float lBv = tB * 0.25f;
            float nm = fmaxf(m, fmaxf(lA, lBv));
            float sc = __expf(m - nm);
            float wA = __expf(lA - nm);
            float wB = __expf(lBv - nm);
            acc = acc * sc + wA * (vA + eA) + wB * (vB + eB);
            l   = l * sc + wA + wB;
            m   = nm;
        }
        for (; i < iend; i++) {
            int2 p = cpair[i];
            const float4* ea4 = (const float4*)(ea + (size_t)p.y * 8);
            float4 u0 = ea4[0], u1 = ea4[1];
            float el = wer[0] * u0.x + wer[1] * u0.y + wer[2] * u0.z + wer[3] * u0.w
                     + wer[4] * u1.x + wer[5] * u1.y + wer[6] * u1.z + wer[7] * u1.w;
            float kl = k1[(size_t)p.x * 64 + lane];
            float tq = ql * (kl + el);
            tq += __shfl_xor(tq, 1, 16);
            tq += __shfl_xor(tq, 2, 16);
            tq += __shfl_xor(tq, 4, 16);
            tq += __shfl_xor(tq, 8, 16);
            float logit = tq * 0.25f;
            float nm = fmaxf(m, logit);
            float sc = __expf(m - nm);
            float wv = __expf(logit - nm);
            float vl = v1[(size_t)p.x * 64 + lane];
            acc = acc * sc + wv * (vl + el);
            l   = l * sc + wv;
            m   = nm;
        }
        sm[w][lane] = m; sl[w][lane] = l; sa[w][lane] = acc;
        __syncthreads();
        if (w == 0) {
            float M = fmaxf(fmaxf(sm[0][lane], sm[1][lane]), fmaxf(sm[2][lane], sm[3][lane]));
            float L = 0.f, A = 0.f;
#pragma unroll
            for (int ww = 0; ww < 4; ww++) {
                float sc = __expf(sm[ww][lane] - M);
                L += sc * sl[ww][lane];
                A += sc * sa[ww][lane];
            }
            float y = (deg > 0) ? (A / L) : 0.f;
            y += __shfl_xor(y, 16);
            y += __shfl_xor(y, 32);
            y *= 0.25f;
            if (lane < 16) {
                float r = bs[lane];
#pragma unroll
                for (int j = 0; j < 16; j++) r = fmaf(Ws[lane * 16 + j], zz[j], r);
                a1[n * 16 + lane] = y + r;
            }
        }
        __syncthreads();   // sm reuse if a second node follows
    }
}

// ---------------- K_g2: agent nodes only, 8 waves/batch + LDS merge (R4-proven) ----------------

__global__ __launch_bounds__(512) void k_g2(
    const float* __restrict__ ea, const float* __restrict__ a1, const int* __restrict__ agent,
    const float* __restrict__ Wq, const float* __restrict__ bq,
    const float* __restrict__ Wk, const float* __restrict__ bk,
    const float* __restrict__ Wv, const float* __restrict__ bv,
    const float* __restrict__ We, const float* __restrict__ Ws, const float* __restrict__ bs,
    const int* __restrict__ off, const int2* __restrict__ cpair,
    float* __restrict__ out)
{
    __shared__ float sm[8][64], sl[8][64], sa0[8][64], sa1[8][64];
    int b = ((blockIdx.x & 7) << 4) + (blockIdx.x >> 3);
    int lane = threadIdx.x & 63;
    int w = threadIdx.x >> 6;
    int n = b * Nn + agent[b];
    int v0 = lane * 2, v1i = lane * 2 + 1;

    float aa[16];
#pragma unroll
    for (int j = 0; j < 16; j++) aa[j] = a1[n * 16 + j];

    float wk0[16], wk1[16], wv0[16], wv1[16], we0[8], we1[8];
#pragma unroll
    for (int j = 0; j < 16; j++) {
        wk0[j] = Wk[v0 * 16 + j];  wk1[j] = Wk[v1i * 16 + j];
        wv0[j] = Wv[v0 * 16 + j];  wv1[j] = Wv[v1i * 16 + j];
    }
#pragma unroll
    for (int j = 0; j < 8; j++) { we0[j] = We[v0 * 8 + j]; we1[j] = We[v1i * 8 + j]; }

    float q0 = bq[v0], q1v = bq[v1i];
#pragma unroll
    for (int j = 0; j < 16; j++) {
        q0  = fmaf(Wq[v0 * 16 + j],  aa[j], q0);
        q1v = fmaf(Wq[v1i * 16 + j], aa[j], q1v);
    }

    int o0 = off[n];
    int deg = off[n + 1] - o0;

    float m = -1e30f, l = 0.f, a0 = 0.f, a1c = 0.f;
    for (int i = w; i < deg; i += 8) {
        int2 p = cpair[o0 + i];
        float as[16];
#pragma unroll
        for (int j = 0; j < 16; j++) as[j] = a1[(size_t)p.x * 16 + j];
        const float4* ea4 = (const float4*)(ea + (size_t)p.y * 8);
        float4 u0 = ea4[0], u1 = ea4[1];
        float eav[8] = {u0.x, u0.y, u0.z, u0.w, u1.x, u1.y, u1.z, u1.w};

        float k0 = bk[v0], k1v = bk[v1i], vv0 = bv[v0], vv1 = bv[v1i];
#pragma unroll
        for (int j = 0; j < 16; j++) {
            k0  = fmaf(wk0[j], as[j], k0);
            k1v = fmaf(wk1[j], as[j], k1v);
            vv0 = fmaf(wv0[j], as[j], vv0);
            vv1 = fmaf(wv1[j], as[j], vv1);
        }
        float e0 = 0.f, e1 = 0.f;
#pragma unroll
        for (int j = 0; j < 8; j++) { e0 = fmaf(we0[j], eav[j], e0); e1 = fmaf(we1[j], eav[j], e1); }

        float t = q0 * (k0 + e0) + q1v * (k1v + e1);
        t += __shfl_xor(t, 1, 16);
        t += __shfl_xor(t, 2, 16);
        t += __shfl_xor(t, 4, 16);
        t += __shfl_xor(t, 8, 16);
        float logit = t * 0.17677669529663687f;  // 1/sqrt(32)
        float nm = fmaxf(m, logit);
        float sc = __expf(m - nm);
        float wgt = __expf(logit - nm);
        a0  = a0 * sc + wgt * (vv0 + e0);
        a1c = a1c * sc + wgt * (vv1 + e1);
        l   = l * sc + wgt;
        m   = nm;
    }
    sm[w][lane] = m; sl[w][lane] = l; sa0[w][lane] = a0; sa1[w][lane] = a1c;
    __syncthreads();
    if (w == 0) {
        float M = sm[0][lane];
#pragma unroll
        for (int ww = 1; ww < 8; ww++) M = fmaxf(M, sm[ww][lane]);
        float L = 0.f, A0 = 0.f, A1 = 0.f;
#pragma unroll
        for (int ww = 0; ww < 8; ww++) {
            float sc = __expf(sm[ww][lane] - M);
            L  += sc * sl[ww][lane];
            A0 += sc * sa0[ww][lane];
            A1 += sc * sa1[ww][lane];
        }
        float y0 = (deg > 0) ? (A0 / L) : 0.f;
        float y1 = (deg > 0) ? (A1 / L) : 0.f;
        y0 += __shfl_xor(y0, 16); y0 += __shfl_xor(y0, 32);
        y1 += __shfl_xor(y1, 16); y1 += __shfl_xor(y1, 32);
        y0 *= 0.25f; y1 *= 0.25f;

        if (lane < 16) {
            int c0 = lane * 2, c1 = lane * 2 + 1;
            float r0 = bs[c0], r1 = bs[c1];
#pragma unroll
            for (int j = 0; j < 16; j++) {
                r0 = fmaf(Ws[c0 * 16 + j], aa[j], r0);
                r1 = fmaf(Ws[c1 * 16 + j], aa[j], r1);
            }
            out[b * 32 + c0] = fmaxf(y0 + r0, 0.f);
            out[b * 32 + c1] = fmaxf(y1 + r1, 0.f);
        }
    }
}

// ---------------- launch ----------------

extern "C" void kernel_launch(void* const* d_in, const int* in_sizes, int n_in,
                              void* d_out, int out_size, void* d_ws, size_t ws_size,
                              hipStream_t stream) {
    (void)in_sizes; (void)n_in; (void)out_size; (void)ws_size;
    const float* nf    = (const float*)d_in[0];
    const int*   ei    = (const int*)d_in[1];
    const float* ea    = (const float*)d_in[2];
    const int*   agent = (const int*)d_in[3];
    const float* ee    = (const float*)d_in[4];
    const float* W1    = (const float*)d_in[5];
    const float* b1    = (const float*)d_in[6];
    const float* W2    = (const float*)d_in[7];
    const float* b2    = (const float*)d_in[8];
    const float* W3    = (const float*)d_in[9];
    const float* b3    = (const float*)d_in[10];
    const float* lg    = (const float*)d_in[11];
    const float* lb    = (const float*)d_in[12];
    const float* g1Wq  = (const float*)d_in[13];
    const float* g1bq  = (const float*)d_in[14];
    const float* g1Wk  = (const float*)d_in[15];
    const float* g1bk  = (const float*)d_in[16];
    const float* g1Wv  = (const float*)d_in[17];
    const float* g1bv  = (const float*)d_in[18];
    const float* g1We  = (const float*)d_in[19];
    const float* g1Ws  = (const float*)d_in[20];
    const float* g1bs  = (const float*)d_in[21];
    const float* g2Wq  = (const float*)d_in[22];
    const float* g2bq  = (const float*)d_in[23];
    const float* g2Wk  = (const float*)d_in[24];
    const float* g2bk  = (const float*)d_in[25];
    const float* g2Wv  = (const float*)d_in[26];
    const float* g2bv  = (const float*)d_in[27];
    const float* g2We  = (const float*)d_in[28];
    const float* g2Ws  = (const float*)d_in[29];
    const float* g2bs  = (const float*)d_in[30];
    float* out = (float*)d_out;

    char* w = (char*)d_ws;
    int* off   = (int*)w;  w += (size_t)(NTOT + 4) * 4;
    w = (char*)(((uintptr_t)w + 15) & ~(uintptr_t)15);
    int2* cpair = (int2*)w; w += (size_t)ETOT * 8;
    float* z   = (float*)w; w += (size_t)NTOT * 16 * 4;
    float* k1  = (float*)w; w += (size_t)NTOT * 64 * 4;
    float* v1  = (float*)w; w += (size_t)NTOT * 64 * 4;
    float* a1  = (float*)w; w += (size_t)NTOT * 16 * 4;
    int* mlist = (int*)w;  w += (size_t)NTOT * 4;
    int* mcnt  = (int*)w;  w += (size_t)Bb * 4;

    k_cmz<<<dim3(Bb), dim3(512), 0, stream>>>(
        ei, agent, nf, ea, ee,
        W1, b1, W2, b2, W3, b3, lg, lb,
        g1Wk, g1bk, g1Wv, g1bv,
        off, cpair, mlist, mcnt, z, k1, v1);
    k_attn1<<<dim3(Bb * 50), dim3(256), 0, stream>>>(
        ea, k1, v1, z, mlist, mcnt,
        g1Wq, g1bq, g1We, g1Ws, g1bs,
        off, cpair, a1);
    k_g2<<<dim3(Bb), dim3(512), 0, stream>>>(
        ea, a1, agent, g2Wq, g2bq, g2Wk, g2bk, g2Wv, g2bv, g2We, g2Ws, g2bs,
        off, cpair, out);
}

// Round 9
// 199.601 us; speedup vs baseline: 1.9916x; 1.9916x over previous
//
#include <hip/hip_runtime.h>
#include <math.h>
#include <stdint.h>

#define Bb   128
#define Nn   100
#define Ee   3200
#define NTOT (Bb*Nn)    // 12800
#define ETOT (Bb*Ee)    // 409600

// XCD swizzle: blockIdx&7 -> XCD (dispatch round-robin over 8 XCDs).
// Batch b lives on XCD b/16 across all kernels: producers and consumers of a
// batch's intermediates (cpair, z, k1, v1, a1) share an L2. Perf-only.
//
// Session laws (R1..R8):
//  - TLP-bound workload: wide grids of small decoupled blocks win; per-batch
//    fusion of float-heavy bodies loses (R1 98us, R7 90us, R8 250us).
//  - The MLP body needs ~100 VGPRs: only 256-thread blocks compile clean;
//    512/1024-thread launch bounds squeeze VGPRs -> scratch spills
//    (R3 WRITE 35MB, R5 137MB, R8 VGPR=60).
//  - grid.sync costs device-scope coherence; separate dispatches are the
//    cheap sync primitive (R6: 305us fused vs ~85us split).

// ---------------- K_csr: per-batch CSR + compact marked list (R7-proven) ----------------

__global__ __launch_bounds__(1024) void k_csr(const int* __restrict__ ei,
                                              const int* __restrict__ agent,
                                              int* __restrict__ off,
                                              int2* __restrict__ cpair,
                                              int* __restrict__ mlist,
                                              int* __restrict__ mcnt)
{
    int b = ((blockIdx.x & 7) << 4) + (blockIdx.x >> 3);
    int t = threadIdx.x;
    __shared__ int s_src[Ee];   // 12.8 KB
    __shared__ int s_dst[Ee];   // 12.8 KB
    __shared__ int cnt[128];
    __shared__ int exc[128];
    __shared__ int cur[128];
    __shared__ int smark[Nn], slist[Nn];
    __shared__ int scnt;
    if (t < 128) cnt[t] = 0;
    if (t < Nn)  smark[t] = 0;
    if (t == 0)  scnt = 0;
    __syncthreads();
    const int* eis = ei + (size_t)b * 2 * Ee;       // src row
    const int* eid = eis + Ee;                      // dst row
    for (int e = t; e < Ee; e += 1024) {
        int s = eis[e];
        int d = eid[e];
        s_src[e] = s;
        s_dst[e] = d;
        atomicAdd(&cnt[d], 1);
    }
    __syncthreads();
    // single-wave exclusive scan of cnt[128]: lane l owns elements 2l, 2l+1
    if (t < 64) {
        int c0 = cnt[2 * t];
        int c1 = cnt[2 * t + 1];
        int p = c0 + c1;
#pragma unroll
        for (int d = 1; d < 64; d <<= 1) {
            int v = __shfl_up(p, d);
            if (t >= d) p += v;
        }
        exc[2 * t]     = p - c0 - c1;
        exc[2 * t + 1] = p - c1;
        cur[2 * t]     = p - c0 - c1;
        cur[2 * t + 1] = p - c1;
    }
    __syncthreads();
    if (t < Nn) off[b * Nn + t] = b * Ee + exc[t];
    if (b == Bb - 1 && t == 0) off[NTOT] = ETOT;
    for (int e = t; e < Ee; e += 1024) {
        int d = s_dst[e];
        int idx = atomicAdd(&cur[d], 1);
        cpair[b * Ee + idx] = make_int2(s_src[e] + b * Nn, b * Ee + e);
    }
    // compact marked list: agent node + srcs of its in-edges (LDS, no re-read)
    int an = agent[b];
    if (t == 0) {
        int old = atomicExch(&smark[an], 1);
        if (!old) { int ix = atomicAdd(&scnt, 1); slist[ix] = an; }
    }
    for (int e = t; e < Ee; e += 1024) {
        if (s_dst[e] == an) {
            int s = s_src[e];
            int old = atomicExch(&smark[s], 1);
            if (!old) { int ix = atomicAdd(&scnt, 1); slist[ix] = s; }
        }
    }
    __syncthreads();
    if (t < scnt) mlist[b * Nn + t] = slist[t];
    if (t == 0)   mcnt[b] = scnt;
}

// ---------------- K_mlpz: edge-MLP + node-sum + k/v, 32-lane node groups ----------------
// Mean deg = Ee/Nn = 32: a 64-lane wave per node idles ~half its lanes.
// Here each wave serves TWO nodes (sub-wave = lane&31): butterfly width 32,
// then each lane produces 2 k/v channels (lane32, lane32+32). 256-thread
// blocks on a 1600-block grid -- inside the proven spill-free regime.

__device__ __forceinline__ void ln_reg(float* h, const float* __restrict__ g,
                                       const float* __restrict__ b) {
    float s = 0.f;
#pragma unroll
    for (int c = 0; c < 16; c++) s += h[c];
    float m = s * 0.0625f;
    float v = 0.f;
#pragma unroll
    for (int c = 0; c < 16; c++) { float d = h[c] - m; v += d * d; }
    float r = rsqrtf(v * 0.0625f + 1e-5f);
#pragma unroll
    for (int c = 0; c < 16; c++) h[c] = (h[c] - m) * r * g[c] + b[c];
}

__global__ __launch_bounds__(256) void k_mlpz(
    const float* __restrict__ nf, const float* __restrict__ ea, const float* __restrict__ ee,
    const float* __restrict__ W1, const float* __restrict__ b1,
    const float* __restrict__ W2, const float* __restrict__ b2,
    const float* __restrict__ W3, const float* __restrict__ b3,
    const float* __restrict__ lg, const float* __restrict__ lb,
    const float* __restrict__ Wk, const float* __restrict__ bk,
    const float* __restrict__ Wv, const float* __restrict__ bv,
    const int* __restrict__ off, const int2* __restrict__ cpair,
    float* __restrict__ z, float* __restrict__ k1, float* __restrict__ v1)
{
    int t   = threadIdx.x;
    int l32 = t & 31;
    int grp = t >> 5;     // 0..7 node groups per block
    int n   = (blockIdx.x & 7) * (NTOT / 8) + (blockIdx.x >> 3) * 8 + grp;

    int o0 = off[n];
    int deg = off[n + 1] - o0;
    int chunks = (deg + 31) >> 5;    // group-local: no cross coupling

    float zs[16];
#pragma unroll
    for (int c = 0; c < 16; c++) zs[c] = 0.f;

    for (int ch = 0; ch < chunks; ch++) {
        int i = ch * 32 + l32;
        float h3[16];
        if (i < deg) {
            int2 p = cpair[o0 + i];
            int et = (int)nf[p.x];
            float in[12];
#pragma unroll
            for (int j = 0; j < 4; j++) in[j] = ee[et * 4 + j];
            const float4* ea4 = (const float4*)(ea + (size_t)p.y * 8);
            float4 ua = ea4[0], ub = ea4[1];
            in[4] = ua.x; in[5] = ua.y; in[6] = ua.z; in[7] = ua.w;
            in[8] = ub.x; in[9] = ub.y; in[10] = ub.z; in[11] = ub.w;

            float h1[16];
#pragma unroll
            for (int c = 0; c < 16; c++) {
                float s = b1[c];
#pragma unroll
                for (int j = 0; j < 12; j++) s = fmaf(W1[c * 12 + j], in[j], s);
                h1[c] = fmaxf(s, 0.f);
            }
            ln_reg(h1, lg, lb);
            float h2[16];
#pragma unroll
            for (int c = 0; c < 16; c++) {
                float s = b2[c];
#pragma unroll
                for (int j = 0; j < 16; j++) s = fmaf(W2[c * 16 + j], h1[j], s);
                h2[c] = fmaxf(s, 0.f);
            }
            ln_reg(h2, lg, lb);
#pragma unroll
            for (int c = 0; c < 16; c++) {
                float s = b3[c];
#pragma unroll
                for (int j = 0; j < 16; j++) s = fmaf(W3[c * 16 + j], h2[j], s);
                h3[c] = fmaxf(s, 0.f);
            }
            ln_reg(h3, lg, lb);
        } else {
#pragma unroll
            for (int c = 0; c < 16; c++) h3[c] = 0.f;
        }
        // 32-lane butterfly per channel: whole sub-wave ends with the full sum
#pragma unroll
        for (int c = 0; c < 16; c++) {
            float s = h3[c];
            s += __shfl_xor(s, 1, 32);
            s += __shfl_xor(s, 2, 32);
            s += __shfl_xor(s, 4, 32);
            s += __shfl_xor(s, 8, 32);
            s += __shfl_xor(s, 16, 32);
            zs[c] += s;
        }
    }

    // z write: compile-time index into zs (keeps zs in registers)
#pragma unroll
    for (int c = 0; c < 16; c++) if (l32 == c) z[n * 16 + c] = zs[c];

    // k/v: every lane holds all z channels -> 2 channels per lane, no shfl
    int c0 = l32, c1 = l32 + 32;
    float ak0 = bk[c0], ak1 = bk[c1], av0 = bv[c0], av1 = bv[c1];
#pragma unroll
    for (int j = 0; j < 16; j++) {
        ak0 = fmaf(Wk[c0 * 16 + j], zs[j], ak0);
        ak1 = fmaf(Wk[c1 * 16 + j], zs[j], ak1);
        av0 = fmaf(Wv[c0 * 16 + j], zs[j], av0);
        av1 = fmaf(Wv[c1 * 16 + j], zs[j], av1);
    }
    k1[n * 64 + c0] = ak0;
    k1[n * 64 + c1] = ak1;
    v1[n * 64 + c0] = av0;
    v1[n * 64 + c1] = av1;
}

// ---------------- K_attn1: g1 attention, one block per marked node (compact list) ----------------
// Grid 128x50: block (b, rep) handles marked idx {rep, rep+50}; dead blocks
// cost one scalar mcnt read (vs 8533 full dead blocks in the mark[] form).
// 4 waves split the node's edges (contiguous quarters), online-softmax each,
// associative LDS merge. Gathers hit the producing XCD's L2 (no staging).

__global__ __launch_bounds__(256) void k_attn1(
    const float* __restrict__ ea,
    const float* __restrict__ k1, const float* __restrict__ v1,
    const float* __restrict__ z,
    const int* __restrict__ mlist, const int* __restrict__ mcnt,
    const float* __restrict__ Wq, const float* __restrict__ bq,
    const float* __restrict__ We, const float* __restrict__ Ws, const float* __restrict__ bs,
    const int* __restrict__ off, const int2* __restrict__ cpair,
    float* __restrict__ a1)
{
    __shared__ float sm[4][64], sl[4][64], sa[4][64];
    int bl   = blockIdx.x & 127;
    int rep  = blockIdx.x >> 7;               // 0..49
    int b    = ((bl & 7) << 4) + (bl >> 3);
    int lane = threadIdx.x & 63;
    int w    = threadIdx.x >> 6;
    int mc   = mcnt[b];

    float wq[16], wer[8];
#pragma unroll
    for (int j = 0; j < 16; j++) wq[j] = Wq[lane * 16 + j];
#pragma unroll
    for (int j = 0; j < 8; j++) wer[j] = We[lane * 8 + j];
    float bq1 = bq[lane];

    for (int ix = rep; ix < mc; ix += 50) {
        int n = b * Nn + mlist[b * Nn + ix];

        float zz[16];
#pragma unroll
        for (int j = 0; j < 16; j++) zz[j] = z[n * 16 + j];
        float ql = bq1;
#pragma unroll
        for (int j = 0; j < 16; j++) ql = fmaf(wq[j], zz[j], ql);

        int o0  = off[n];
        int deg = off[n + 1] - o0;
        int i    = o0 + ((deg * w) >> 2);       // contiguous quarter per wave
        int iend = o0 + ((deg * (w + 1)) >> 2);

        float m = -1e30f, l = 0.f, acc = 0.f;
        for (; i + 2 <= iend; i += 2) {
            int2 pA = cpair[i];
            int2 pB = cpair[i + 1];
            const float4* eaA = (const float4*)(ea + (size_t)pA.y * 8);
            const float4* eaB = (const float4*)(ea + (size_t)pB.y * 8);
            float4 a0v = eaA[0], a1v = eaA[1], b0v = eaB[0], b1v = eaB[1];
            float eA = wer[0] * a0v.x + wer[1] * a0v.y + wer[2] * a0v.z + wer[3] * a0v.w
                     + wer[4] * a1v.x + wer[5] * a1v.y + wer[6] * a1v.z + wer[7] * a1v.w;
            float eB = wer[0] * b0v.x + wer[1] * b0v.y + wer[2] * b0v.z + wer[3] * b0v.w
                     + wer[4] * b1v.x + wer[5] * b1v.y + wer[6] * b1v.z + wer[7] * b1v.w;
            float kA = k1[(size_t)pA.x * 64 + lane];
            float kB = k1[(size_t)pB.x * 64 + lane];
            float vA = v1[(size_t)pA.x * 64 + lane];
            float vB = v1[(size_t)pB.x * 64 + lane];
            float tA = ql * (kA + eA);
            float tB = ql * (kB + eB);
            tA += __shfl_xor(tA, 1, 16);  tB += __shfl_xor(tB, 1, 16);
            tA += __shfl_xor(tA, 2, 16);  tB += __shfl_xor(tB, 2, 16);
            tA += __shfl_xor(tA, 4, 16);  tB += __shfl_xor(tB, 4, 16);
            tA += __shfl_xor(tA, 8, 16);  tB += __shfl_xor(tB, 8, 16);
            float lA  = tA * 0.25f;
            float lBv = tB * 0.25f;
            float nm = fmaxf(m, fmaxf(lA, lBv));
            float sc = __expf(m - nm);
            float wA = __expf(lA - nm);
            float wB = __expf(lBv - nm);
            acc = acc * sc + wA * (vA + eA) + wB * (vB + eB);
            l   = l * sc + wA + wB;
            m   = nm;
        }
        for (; i < iend; i++) {
            int2 p = cpair[i];
            const float4* ea4 = (const float4*)(ea + (size_t)p.y * 8);
            float4 u0 = ea4[0], u1 = ea4[1];
            float el = wer[0] * u0.x + wer[1] * u0.y + wer[2] * u0.z + wer[3] * u0.w
                     + wer[4] * u1.x + wer[5] * u1.y + wer[6] * u1.z + wer[7] * u1.w;
            float kl = k1[(size_t)p.x * 64 + lane];
            float tq = ql * (kl + el);
            tq += __shfl_xor(tq, 1, 16);
            tq += __shfl_xor(tq, 2, 16);
            tq += __shfl_xor(tq, 4, 16);
            tq += __shfl_xor(tq, 8, 16);
            float logit = tq * 0.25f;
            float nm = fmaxf(m, logit);
            float sc = __expf(m - nm);
            float wv = __expf(logit - nm);
            float vl = v1[(size_t)p.x * 64 + lane];
            acc = acc * sc + wv * (vl + el);
            l   = l * sc + wv;
            m   = nm;
        }
        sm[w][lane] = m; sl[w][lane] = l; sa[w][lane] = acc;
        __syncthreads();
        if (w == 0) {
            float M = fmaxf(fmaxf(sm[0][lane], sm[1][lane]), fmaxf(sm[2][lane], sm[3][lane]));
            float L = 0.f, A = 0.f;
#pragma unroll
            for (int ww = 0; ww < 4; ww++) {
                float sc = __expf(sm[ww][lane] - M);
                L += sc * sl[ww][lane];
                A += sc * sa[ww][lane];
            }
            float y = (deg > 0) ? (A / L) : 0.f;
            y += __shfl_xor(y, 16);
            y += __shfl_xor(y, 32);
            y *= 0.25f;
            if (lane < 16) {
                float r = bs[lane];
#pragma unroll
                for (int j = 0; j < 16; j++) r = fmaf(Ws[lane * 16 + j], zz[j], r);
                a1[n * 16 + lane] = y + r;
            }
        }
        __syncthreads();   // sm reuse if a second node follows
    }
}

// ---------------- K_g2: agent nodes only, 8 waves/batch + LDS merge (R4-proven) ----------------

__global__ __launch_bounds__(512) void k_g2(
    const float* __restrict__ ea, const float* __restrict__ a1, const int* __restrict__ agent,
    const float* __restrict__ Wq, const float* __restrict__ bq,
    const float* __restrict__ Wk, const float* __restrict__ bk,
    const float* __restrict__ Wv, const float* __restrict__ bv,
    const float* __restrict__ We, const float* __restrict__ Ws, const float* __restrict__ bs,
    const int* __restrict__ off, const int2* __restrict__ cpair,
    float* __restrict__ out)
{
    __shared__ float sm[8][64], sl[8][64], sa0[8][64], sa1[8][64];
    int b = ((blockIdx.x & 7) << 4) + (blockIdx.x >> 3);
    int lane = threadIdx.x & 63;
    int w = threadIdx.x >> 6;
    int n = b * Nn + agent[b];
    int v0 = lane * 2, v1i = lane * 2 + 1;

    float aa[16];
#pragma unroll
    for (int j = 0; j < 16; j++) aa[j] = a1[n * 16 + j];

    float wk0[16], wk1[16], wv0[16], wv1[16], we0[8], we1[8];
#pragma unroll
    for (int j = 0; j < 16; j++) {
        wk0[j] = Wk[v0 * 16 + j];  wk1[j] = Wk[v1i * 16 + j];
        wv0[j] = Wv[v0 * 16 + j];  wv1[j] = Wv[v1i * 16 + j];
    }
#pragma unroll
    for (int j = 0; j < 8; j++) { we0[j] = We[v0 * 8 + j]; we1[j] = We[v1i * 8 + j]; }

    float q0 = bq[v0], q1v = bq[v1i];
#pragma unroll
    for (int j = 0; j < 16; j++) {
        q0  = fmaf(Wq[v0 * 16 + j],  aa[j], q0);
        q1v = fmaf(Wq[v1i * 16 + j], aa[j], q1v);
    }

    int o0 = off[n];
    int deg = off[n + 1] - o0;

    float m = -1e30f, l = 0.f, a0 = 0.f, a1c = 0.f;
    for (int i = w; i < deg; i += 8) {
        int2 p = cpair[o0 + i];
        float as[16];
#pragma unroll
        for (int j = 0; j < 16; j++) as[j] = a1[(size_t)p.x * 16 + j];
        const float4* ea4 = (const float4*)(ea + (size_t)p.y * 8);
        float4 u0 = ea4[0], u1 = ea4[1];
        float eav[8] = {u0.x, u0.y, u0.z, u0.w, u1.x, u1.y, u1.z, u1.w};

        float k0 = bk[v0], k1v = bk[v1i], vv0 = bv[v0], vv1 = bv[v1i];
#pragma unroll
        for (int j = 0; j < 16; j++) {
            k0  = fmaf(wk0[j], as[j], k0);
            k1v = fmaf(wk1[j], as[j], k1v);
            vv0 = fmaf(wv0[j], as[j], vv0);
            vv1 = fmaf(wv1[j], as[j], vv1);
        }
        float e0 = 0.f, e1 = 0.f;
#pragma unroll
        for (int j = 0; j < 8; j++) { e0 = fmaf(we0[j], eav[j], e0); e1 = fmaf(we1[j], eav[j], e1); }

        float t = q0 * (k0 + e0) + q1v * (k1v + e1);
        t += __shfl_xor(t, 1, 16);
        t += __shfl_xor(t, 2, 16);
        t += __shfl_xor(t, 4, 16);
        t += __shfl_xor(t, 8, 16);
        float logit = t * 0.17677669529663687f;  // 1/sqrt(32)
        float nm = fmaxf(m, logit);
        float sc = __expf(m - nm);
        float wgt = __expf(logit - nm);
        a0  = a0 * sc + wgt * (vv0 + e0);
        a1c = a1c * sc + wgt * (vv1 + e1);
        l   = l * sc + wgt;
        m   = nm;
    }
    sm[w][lane] = m; sl[w][lane] = l; sa0[w][lane] = a0; sa1[w][lane] = a1c;
    __syncthreads();
    if (w == 0) {
        float M = sm[0][lane];
#pragma unroll
        for (int ww = 1; ww < 8; ww++) M = fmaxf(M, sm[ww][lane]);
        float L = 0.f, A0 = 0.f, A1 = 0.f;
#pragma unroll
        for (int ww = 0; ww < 8; ww++) {
            float sc = __expf(sm[ww][lane] - M);
            L  += sc * sl[ww][lane];
            A0 += sc * sa0[ww][lane];
            A1 += sc * sa1[ww][lane];
        }
        float y0 = (deg > 0) ? (A0 / L) : 0.f;
        float y1 = (deg > 0) ? (A1 / L) : 0.f;
        y0 += __shfl_xor(y0, 16); y0 += __shfl_xor(y0, 32);
        y1 += __shfl_xor(y1, 16); y1 += __shfl_xor(y1, 32);
        y0 *= 0.25f; y1 *= 0.25f;

        if (lane < 16) {
            int c0 = lane * 2, c1 = lane * 2 + 1;
            float r0 = bs[c0], r1 = bs[c1];
#pragma unroll
            for (int j = 0; j < 16; j++) {
                r0 = fmaf(Ws[c0 * 16 + j], aa[j], r0);
                r1 = fmaf(Ws[c1 * 16 + j], aa[j], r1);
            }
            out[b * 32 + c0] = fmaxf(y0 + r0, 0.f);
            out[b * 32 + c1] = fmaxf(y1 + r1, 0.f);
        }
    }
}

// ---------------- launch ----------------

extern "C" void kernel_launch(void* const* d_in, const int* in_sizes, int n_in,
                              void* d_out, int out_size, void* d_ws, size_t ws_size,
                              hipStream_t stream) {
    (void)in_sizes; (void)n_in; (void)out_size; (void)ws_size;
    const float* nf    = (const float*)d_in[0];
    const int*   ei    = (const int*)d_in[1];
    const float* ea    = (const float*)d_in[2];
    const int*   agent = (const int*)d_in[3];
    const float* ee    = (const float*)d_in[4];
    const float* W1    = (const float*)d_in[5];
    const float* b1    = (const float*)d_in[6];
    const float* W2    = (const float*)d_in[7];
    const float* b2    = (const float*)d_in[8];
    const float* W3    = (const float*)d_in[9];
    const float* b3    = (const float*)d_in[10];
    const float* lg    = (const float*)d_in[11];
    const float* lb    = (const float*)d_in[12];
    const float* g1Wq  = (const float*)d_in[13];
    const float* g1bq  = (const float*)d_in[14];
    const float* g1Wk  = (const float*)d_in[15];
    const float* g1bk  = (const float*)d_in[16];
    const float* g1Wv  = (const float*)d_in[17];
    const float* g1bv  = (const float*)d_in[18];
    const float* g1We  = (const float*)d_in[19];
    const float* g1Ws  = (const float*)d_in[20];
    const float* g1bs  = (const float*)d_in[21];
    const float* g2Wq  = (const float*)d_in[22];
    const float* g2bq  = (const float*)d_in[23];
    const float* g2Wk  = (const float*)d_in[24];
    const float* g2bk  = (const float*)d_in[25];
    const float* g2Wv  = (const float*)d_in[26];
    const float* g2bv  = (const float*)d_in[27];
    const float* g2We  = (const float*)d_in[28];
    const float* g2Ws  = (const float*)d_in[29];
    const float* g2bs  = (const float*)d_in[30];
    float* out = (float*)d_out;

    char* w = (char*)d_ws;
    int* off   = (int*)w;  w += (size_t)(NTOT + 4) * 4;
    w = (char*)(((uintptr_t)w + 15) & ~(uintptr_t)15);
    int2* cpair = (int2*)w; w += (size_t)ETOT * 8;
    float* z   = (float*)w; w += (size_t)NTOT * 16 * 4;
    float* k1  = (float*)w; w += (size_t)NTOT * 64 * 4;
    float* v1  = (float*)w; w += (size_t)NTOT * 64 * 4;
    float* a1  = (float*)w; w += (size_t)NTOT * 16 * 4;
    int* mlist = (int*)w;  w += (size_t)NTOT * 4;
    int* mcnt  = (int*)w;  w += (size_t)Bb * 4;

    k_csr<<<dim3(Bb), dim3(1024), 0, stream>>>(ei, agent, off, cpair, mlist, mcnt);
    k_mlpz<<<dim3(NTOT / 8), dim3(256), 0, stream>>>(
        nf, ea, ee, W1, b1, W2, b2, W3, b3, lg, lb,
        g1Wk, g1bk, g1Wv, g1bv,
        off, cpair, z, k1, v1);
    k_attn1<<<dim3(Bb * 50), dim3(256), 0, stream>>>(
        ea, k1, v1, z, mlist, mcnt,
        g1Wq, g1bq, g1We, g1Ws, g1bs,
        off, cpair, a1);
    k_g2<<<dim3(Bb), dim3(512), 0, stream>>>(
        ea, a1, agent, g2Wq, g2bq, g2Wk, g2bk, g2Wv, g2bv, g2We, g2Ws, g2bs,
        off, cpair, out);
}

// Round 10
// 192.938 us; speedup vs baseline: 2.0604x; 1.0345x over previous
//
#include <hip/hip_runtime.h>
#include <math.h>
#include <stdint.h>

#define Bb   128
#define Nn   100
#define Ee   3200
#define NTOT (Bb*Nn)    // 12800
#define ETOT (Bb*Ee)    // 409600

// XCD swizzle: blockIdx&7 -> XCD (dispatch round-robin over 8 XCDs).
// Batch b lives on XCD b/16 across all kernels: producers and consumers of a
// batch's intermediates (cpair, z, k1, v1, a1) share an L2. Perf-only.
//
// Session laws (R1..R9) -- this is the empirical best shape (R4, 193.7us):
//  - TLP-bound: wide grids of small decoupled blocks win; per-batch fusion of
//    float-heavy bodies loses (R1 98us, R7 90us, R8 250us).
//  - MLP body needs ~100 VGPRs: only 256-thread blocks compile spill-free
//    (R3 WRITE 35MB, R5 137MB, R8 VGPR=60 all spilled at >=512 threads).
//  - grid.sync costs device-scope coherence on 8 XCDs; separate dispatches
//    are the cheap sync primitive (R6: 305us fused vs ~85us split).
//  - Body micro-opts inside this shape move <= +-6us ~= run-to-run noise
//    (R4 vs R9); remaining time is harness fixed cost (~110us) + 4 dependent
//    dispatch latencies.

// ---------------- K_csr: per-batch CSR build + mark ----------------

__global__ __launch_bounds__(1024) void k_csr(const int* __restrict__ ei,
                                              const int* __restrict__ agent,
                                              int* __restrict__ off,
                                              int2* __restrict__ cpair,
                                              int* __restrict__ mark)
{
    int b = ((blockIdx.x & 7) << 4) + (blockIdx.x >> 3);
    int t = threadIdx.x;
    __shared__ int s_src[Ee];   // 12.8 KB
    __shared__ int s_dst[Ee];   // 12.8 KB
    __shared__ int cnt[128];
    __shared__ int exc[128];
    __shared__ int cur[128];
    if (t < 128) cnt[t] = 0;
    if (t < Nn) mark[b * Nn + t] = 0;
    __syncthreads();
    const int* eis = ei + (size_t)b * 2 * Ee;       // src row
    const int* eid = eis + Ee;                      // dst row
    for (int e = t; e < Ee; e += 1024) {
        int s = eis[e];
        int d = eid[e];
        s_src[e] = s;
        s_dst[e] = d;
        atomicAdd(&cnt[d], 1);
    }
    __syncthreads();
    // single-wave exclusive scan of cnt[128]: lane l owns elements 2l, 2l+1
    if (t < 64) {
        int c0 = cnt[2 * t];
        int c1 = cnt[2 * t + 1];
        int p = c0 + c1;                       // pair sum
#pragma unroll
        for (int d = 1; d < 64; d <<= 1) {
            int v = __shfl_up(p, d);
            if (t >= d) p += v;                // inclusive scan of pair sums
        }
        exc[2 * t]     = p - c0 - c1;          // exclusive prefix
        exc[2 * t + 1] = p - c1;
        cur[2 * t]     = p - c0 - c1;
        cur[2 * t + 1] = p - c1;
    }
    __syncthreads();
    if (t < Nn) off[b * Nn + t] = b * Ee + exc[t];
    if (b == Bb - 1 && t == 0) off[NTOT] = ETOT;
    for (int e = t; e < Ee; e += 1024) {
        int d = s_dst[e];
        int idx = atomicAdd(&cur[d], 1);
        cpair[b * Ee + idx] = make_int2(s_src[e] + b * Nn, b * Ee + e);
    }
    // mark = agent node + srcs of its in-edges (from LDS, no global re-read)
    int an = agent[b];
    if (t == 0) mark[b * Nn + an] = 1;
    for (int e = t; e < Ee; e += 1024) {
        if (s_dst[e] == an) mark[b * Nn + s_src[e]] = 1;
    }
}

// ---------------- K_mlpz: fused edge-MLP + node-sum + k/v ----------------
// One wave per node, waves fully decoupled: z-reduction is a 64-lane
// shfl_xor butterfly (no LDS, no barriers, no cross-wave mdeg coupling).
// Every lane ends holding all 16 z channels -> k/v matvec needs no shfl.

__device__ __forceinline__ void ln_reg(float* h, const float* __restrict__ g,
                                       const float* __restrict__ b) {
    float s = 0.f;
#pragma unroll
    for (int c = 0; c < 16; c++) s += h[c];
    float m = s * 0.0625f;
    float v = 0.f;
#pragma unroll
    for (int c = 0; c < 16; c++) { float d = h[c] - m; v += d * d; }
    float r = rsqrtf(v * 0.0625f + 1e-5f);
#pragma unroll
    for (int c = 0; c < 16; c++) h[c] = (h[c] - m) * r * g[c] + b[c];
}

__global__ __launch_bounds__(256) void k_mlpz(
    const float* __restrict__ nf, const float* __restrict__ ea, const float* __restrict__ ee,
    const float* __restrict__ W1, const float* __restrict__ b1,
    const float* __restrict__ W2, const float* __restrict__ b2,
    const float* __restrict__ W3, const float* __restrict__ b3,
    const float* __restrict__ lg, const float* __restrict__ lb,
    const float* __restrict__ Wk, const float* __restrict__ bk,
    const float* __restrict__ Wv, const float* __restrict__ bv,
    const int* __restrict__ off, const int2* __restrict__ cpair,
    float* __restrict__ z, float* __restrict__ k1, float* __restrict__ v1)
{
    int lane = threadIdx.x & 63;
    int wid  = threadIdx.x >> 6;
    int n    = (blockIdx.x & 7) * (NTOT / 8) + (blockIdx.x >> 3) * 4 + wid;

    int o0 = off[n];
    int deg = off[n + 1] - o0;
    int chunks = (deg + 63) >> 6;    // wave-local: no cross-wave coupling

    float zs[16];
#pragma unroll
    for (int c = 0; c < 16; c++) zs[c] = 0.f;

    for (int ch = 0; ch < chunks; ch++) {
        int i = ch * 64 + lane;
        float h3[16];
        if (i < deg) {
            int2 p = cpair[o0 + i];
            int et = (int)nf[p.x];
            float in[12];
#pragma unroll
            for (int j = 0; j < 4; j++) in[j] = ee[et * 4 + j];
            const float4* ea4 = (const float4*)(ea + (size_t)p.y * 8);
            float4 ua = ea4[0], ub = ea4[1];
            in[4] = ua.x; in[5] = ua.y; in[6] = ua.z; in[7] = ua.w;
            in[8] = ub.x; in[9] = ub.y; in[10] = ub.z; in[11] = ub.w;

            float h1[16];
#pragma unroll
            for (int c = 0; c < 16; c++) {
                float s = b1[c];
#pragma unroll
                for (int j = 0; j < 12; j++) s = fmaf(W1[c * 12 + j], in[j], s);
                h1[c] = fmaxf(s, 0.f);
            }
            ln_reg(h1, lg, lb);
            float h2[16];
#pragma unroll
            for (int c = 0; c < 16; c++) {
                float s = b2[c];
#pragma unroll
                for (int j = 0; j < 16; j++) s = fmaf(W2[c * 16 + j], h1[j], s);
                h2[c] = fmaxf(s, 0.f);
            }
            ln_reg(h2, lg, lb);
#pragma unroll
            for (int c = 0; c < 16; c++) {
                float s = b3[c];
#pragma unroll
                for (int j = 0; j < 16; j++) s = fmaf(W3[c * 16 + j], h2[j], s);
                h3[c] = fmaxf(s, 0.f);
            }
            ln_reg(h3, lg, lb);
        } else {
#pragma unroll
            for (int c = 0; c < 16; c++) h3[c] = 0.f;
        }
        // 64-lane butterfly sum per channel: all lanes end with the full sum
#pragma unroll
        for (int c = 0; c < 16; c++) {
            float s = h3[c];
            s += __shfl_xor(s, 1);
            s += __shfl_xor(s, 2);
            s += __shfl_xor(s, 4);
            s += __shfl_xor(s, 8);
            s += __shfl_xor(s, 16);
            s += __shfl_xor(s, 32);
            zs[c] += s;
        }
    }

    // z write: compile-time index into zs (keeps zs in registers)
#pragma unroll
    for (int c = 0; c < 16; c++) if (lane == c) z[n * 16 + c] = zs[c];

    // k/v: every lane holds all z channels -> straight matvec, no shfl
    float ak = bk[lane], av = bv[lane];
#pragma unroll
    for (int j = 0; j < 16; j++) {
        ak = fmaf(Wk[lane * 16 + j], zs[j], ak);
        av = fmaf(Wv[lane * 16 + j], zs[j], av);
    }
    k1[n * 64 + lane] = ak;
    v1[n * 64 + lane] = av;
}

// ---------------- K_attn1: g1 attention, one BLOCK per marked node ----------------
// 4 waves split the node's edge list (contiguous quarters), online-softmax
// each, then associative merge in LDS. Gathers hit the producing XCD's L2.

__global__ __launch_bounds__(256) void k_attn1(
    const float* __restrict__ ea,
    const float* __restrict__ k1, const float* __restrict__ v1,
    const float* __restrict__ z, const int* __restrict__ mark,
    const float* __restrict__ Wq, const float* __restrict__ bq,
    const float* __restrict__ We, const float* __restrict__ Ws, const float* __restrict__ bs,
    const int* __restrict__ off, const int2* __restrict__ cpair,
    float* __restrict__ a1)
{
    int n = (blockIdx.x & 7) * (NTOT / 8) + (blockIdx.x >> 3);
    if (!mark[n]) return;   // block-uniform: a1[n] never read for unmarked n

    __shared__ float sm[4][64], sl[4][64], sa[4][64];
    int lane = threadIdx.x & 63;
    int w    = threadIdx.x >> 6;

    float zz[16];
#pragma unroll
    for (int j = 0; j < 16; j++) zz[j] = z[n * 16 + j];
    float ql = bq[lane];
#pragma unroll
    for (int j = 0; j < 16; j++) ql = fmaf(Wq[lane * 16 + j], zz[j], ql);
    float wer[8];
#pragma unroll
    for (int j = 0; j < 8; j++) wer[j] = We[lane * 8 + j];

    int o0  = off[n];
    int deg = off[n + 1] - o0;
    int i    = o0 + ((deg * w) >> 2);       // contiguous quarter per wave
    int iend = o0 + ((deg * (w + 1)) >> 2);

    float m = -1e30f, l = 0.f, acc = 0.f;
    for (; i + 2 <= iend; i += 2) {
        int2 pA = cpair[i];
        int2 pB = cpair[i + 1];
        const float4* eaA = (const float4*)(ea + (size_t)pA.y * 8);
        const float4* eaB = (const float4*)(ea + (size_t)pB.y * 8);
        float4 a0v = eaA[0], a1v = eaA[1], b0v = eaB[0], b1v = eaB[1];
        float eA = wer[0] * a0v.x + wer[1] * a0v.y + wer[2] * a0v.z + wer[3] * a0v.w
                 + wer[4] * a1v.x + wer[5] * a1v.y + wer[6] * a1v.z + wer[7] * a1v.w;
        float eB = wer[0] * b0v.x + wer[1] * b0v.y + wer[2] * b0v.z + wer[3] * b0v.w
                 + wer[4] * b1v.x + wer[5] * b1v.y + wer[6] * b1v.z + wer[7] * b1v.w;
        float kA = k1[(size_t)pA.x * 64 + lane];
        float kB = k1[(size_t)pB.x * 64 + lane];
        float vA = v1[(size_t)pA.x * 64 + lane];
        float vB = v1[(size_t)pB.x * 64 + lane];
        float tA = ql * (kA + eA);
        float tB = ql * (kB + eB);
        tA += __shfl_xor(tA, 1, 16);  tB += __shfl_xor(tB, 1, 16);
        tA += __shfl_xor(tA, 2, 16);  tB += __shfl_xor(tB, 2, 16);
        tA += __shfl_xor(tA, 4, 16);  tB += __shfl_xor(tB, 4, 16);
        tA += __shfl_xor(tA, 8, 16);  tB += __shfl_xor(tB, 8, 16);
        float lA  = tA * 0.25f;
        float lBv = tB * 0.25f;
        float nm = fmaxf(m, fmaxf(lA, lBv));
        float sc = __expf(m - nm);
        float wA = __expf(lA - nm);
        float wB = __expf(lBv - nm);
        acc = acc * sc + wA * (vA + eA) + wB * (vB + eB);
        l   = l * sc + wA + wB;
        m   = nm;
    }
    for (; i < iend; i++) {
        int2 p = cpair[i];
        const float4* ea4 = (const float4*)(ea + (size_t)p.y * 8);
        float4 u0 = ea4[0], u1 = ea4[1];
        float el = wer[0] * u0.x + wer[1] * u0.y + wer[2] * u0.z + wer[3] * u0.w
                 + wer[4] * u1.x + wer[5] * u1.y + wer[6] * u1.z + wer[7] * u1.w;
        float kl = k1[(size_t)p.x * 64 + lane];
        float tq = ql * (kl + el);
        tq += __shfl_xor(tq, 1, 16);
        tq += __shfl_xor(tq, 2, 16);
        tq += __shfl_xor(tq, 4, 16);
        tq += __shfl_xor(tq, 8, 16);
        float logit = tq * 0.25f;
        float nm = fmaxf(m, logit);
        float sc = __expf(m - nm);
        float wv = __expf(logit - nm);
        float vl = v1[(size_t)p.x * 64 + lane];
        acc = acc * sc + wv * (vl + el);
        l   = l * sc + wv;
        m   = nm;
    }
    sm[w][lane] = m; sl[w][lane] = l; sa[w][lane] = acc;
    __syncthreads();
    if (w == 0) {
        float M = fmaxf(fmaxf(sm[0][lane], sm[1][lane]), fmaxf(sm[2][lane], sm[3][lane]));
        float L = 0.f, A = 0.f;
#pragma unroll
        for (int ww = 0; ww < 4; ww++) {
            float sc = __expf(sm[ww][lane] - M);
            L += sc * sl[ww][lane];
            A += sc * sa[ww][lane];
        }
        float y = (deg > 0) ? (A / L) : 0.f;
        y += __shfl_xor(y, 16);
        y += __shfl_xor(y, 32);
        y *= 0.25f;
        if (lane < 16) {
            float r = bs[lane];
#pragma unroll
            for (int j = 0; j < 16; j++) r = fmaf(Ws[lane * 16 + j], zz[j], r);
            a1[n * 16 + lane] = y + r;
        }
    }
}

// ---------------- K_g2: agent nodes only, 8 waves/batch + LDS merge ----------------

__global__ __launch_bounds__(512) void k_g2(
    const float* __restrict__ ea, const float* __restrict__ a1, const int* __restrict__ agent,
    const float* __restrict__ Wq, const float* __restrict__ bq,
    const float* __restrict__ Wk, const float* __restrict__ bk,
    const float* __restrict__ Wv, const float* __restrict__ bv,
    const float* __restrict__ We, const float* __restrict__ Ws, const float* __restrict__ bs,
    const int* __restrict__ off, const int2* __restrict__ cpair,
    float* __restrict__ out)
{
    __shared__ float sm[8][64], sl[8][64], sa0[8][64], sa1[8][64];
    int b = ((blockIdx.x & 7) << 4) + (blockIdx.x >> 3);
    int lane = threadIdx.x & 63;
    int w = threadIdx.x >> 6;
    int n = b * Nn + agent[b];
    int v0 = lane * 2, v1i = lane * 2 + 1;

    float aa[16];
#pragma unroll
    for (int j = 0; j < 16; j++) aa[j] = a1[n * 16 + j];

    float wk0[16], wk1[16], wv0[16], wv1[16], we0[8], we1[8];
#pragma unroll
    for (int j = 0; j < 16; j++) {
        wk0[j] = Wk[v0 * 16 + j];  wk1[j] = Wk[v1i * 16 + j];
        wv0[j] = Wv[v0 * 16 + j];  wv1[j] = Wv[v1i * 16 + j];
    }
#pragma unroll
    for (int j = 0; j < 8; j++) { we0[j] = We[v0 * 8 + j]; we1[j] = We[v1i * 8 + j]; }

    float q0 = bq[v0], q1v = bq[v1i];
#pragma unroll
    for (int j = 0; j < 16; j++) {
        q0  = fmaf(Wq[v0 * 16 + j],  aa[j], q0);
        q1v = fmaf(Wq[v1i * 16 + j], aa[j], q1v);
    }

    int o0 = off[n];
    int deg = off[n + 1] - o0;

    float m = -1e30f, l = 0.f, a0 = 0.f, a1c = 0.f;
    for (int i = w; i < deg; i += 8) {
        int2 p = cpair[o0 + i];
        int src = p.x, ge = p.y;
        float as[16];
#pragma unroll
        for (int j = 0; j < 16; j++) as[j] = a1[(size_t)src * 16 + j];
        const float4* ea4 = (const float4*)(ea + (size_t)ge * 8);
        float4 u0 = ea4[0], u1 = ea4[1];
        float eav[8] = {u0.x, u0.y, u0.z, u0.w, u1.x, u1.y, u1.z, u1.w};

        float k0 = bk[v0], k1v = bk[v1i], vv0 = bv[v0], vv1 = bv[v1i];
#pragma unroll
        for (int j = 0; j < 16; j++) {
            k0  = fmaf(wk0[j], as[j], k0);
            k1v = fmaf(wk1[j], as[j], k1v);
            vv0 = fmaf(wv0[j], as[j], vv0);
            vv1 = fmaf(wv1[j], as[j], vv1);
        }
        float e0 = 0.f, e1 = 0.f;
#pragma unroll
        for (int j = 0; j < 8; j++) { e0 = fmaf(we0[j], eav[j], e0); e1 = fmaf(we1[j], eav[j], e1); }

        float t = q0 * (k0 + e0) + q1v * (k1v + e1);
        t += __shfl_xor(t, 1, 16);
        t += __shfl_xor(t, 2, 16);
        t += __shfl_xor(t, 4, 16);
        t += __shfl_xor(t, 8, 16);
        float logit = t * 0.17677669529663687f;  // / sqrt(32)
        float nm = fmaxf(m, logit);
        float sc = __expf(m - nm);
        float wgt = __expf(logit - nm);
        a0  = a0 * sc + wgt * (vv0 + e0);
        a1c = a1c * sc + wgt * (vv1 + e1);
        l   = l * sc + wgt;
        m   = nm;
    }
    sm[w][lane] = m; sl[w][lane] = l; sa0[w][lane] = a0; sa1[w][lane] = a1c;
    __syncthreads();
    if (w == 0) {
        float M = sm[0][lane];
#pragma unroll
        for (int ww = 1; ww < 8; ww++) M = fmaxf(M, sm[ww][lane]);
        float L = 0.f, A0 = 0.f, A1 = 0.f;
#pragma unroll
        for (int ww = 0; ww < 8; ww++) {
            float sc = __expf(sm[ww][lane] - M);
            L  += sc * sl[ww][lane];
            A0 += sc * sa0[ww][lane];
            A1 += sc * sa1[ww][lane];
        }
        float y0 = (deg > 0) ? (A0 / L) : 0.f;
        float y1 = (deg > 0) ? (A1 / L) : 0.f;
        y0 += __shfl_xor(y0, 16); y0 += __shfl_xor(y0, 32);
        y1 += __shfl_xor(y1, 16); y1 += __shfl_xor(y1, 32);
        y0 *= 0.25f; y1 *= 0.25f;

        if (lane < 16) {
            int c0 = lane * 2, c1 = lane * 2 + 1;
            float r0 = bs[c0], r1 = bs[c1];
#pragma unroll
            for (int j = 0; j < 16; j++) {
                r0 = fmaf(Ws[c0 * 16 + j], aa[j], r0);
                r1 = fmaf(Ws[c1 * 16 + j], aa[j], r1);
            }
            out[b * 32 + c0] = fmaxf(y0 + r0, 0.f);
            out[b * 32 + c1] = fmaxf(y1 + r1, 0.f);
        }
    }
}

// ---------------- launch ----------------

extern "C" void kernel_launch(void* const* d_in, const int* in_sizes, int n_in,
                              void* d_out, int out_size, void* d_ws, size_t ws_size,
                              hipStream_t stream) {
    (void)in_sizes; (void)n_in; (void)out_size; (void)ws_size;
    const float* nf    = (const float*)d_in[0];
    const int*   ei    = (const int*)d_in[1];
    const float* ea    = (const float*)d_in[2];
    const int*   agent = (const int*)d_in[3];
    const float* ee    = (const float*)d_in[4];
    const float* W1    = (const float*)d_in[5];
    const float* b1    = (const float*)d_in[6];
    const float* W2    = (const float*)d_in[7];
    const float* b2    = (const float*)d_in[8];
    const float* W3    = (const float*)d_in[9];
    const float* b3    = (const float*)d_in[10];
    const float* lg    = (const float*)d_in[11];
    const float* lb    = (const float*)d_in[12];
    const float* g1Wq  = (const float*)d_in[13];
    const float* g1bq  = (const float*)d_in[14];
    const float* g1Wk  = (const float*)d_in[15];
    const float* g1bk  = (const float*)d_in[16];
    const float* g1Wv  = (const float*)d_in[17];
    const float* g1bv  = (const float*)d_in[18];
    const float* g1We  = (const float*)d_in[19];
    const float* g1Ws  = (const float*)d_in[20];
    const float* g1bs  = (const float*)d_in[21];
    const float* g2Wq  = (const float*)d_in[22];
    const float* g2bq  = (const float*)d_in[23];
    const float* g2Wk  = (const float*)d_in[24];
    const float* g2bk  = (const float*)d_in[25];
    const float* g2Wv  = (const float*)d_in[26];
    const float* g2bv  = (const float*)d_in[27];
    const float* g2We  = (const float*)d_in[28];
    const float* g2Ws  = (const float*)d_in[29];
    const float* g2bs  = (const float*)d_in[30];
    float* out = (float*)d_out;

    char* w = (char*)d_ws;
    int* mark  = (int*)w;  w += (size_t)NTOT * 4;
    int* off   = (int*)w;  w += (size_t)(NTOT + 4) * 4;
    w = (char*)(((uintptr_t)w + 15) & ~(uintptr_t)15);
    int2* cpair = (int2*)w; w += (size_t)ETOT * 8;
    float* z   = (float*)w; w += (size_t)NTOT * 16 * 4;
    float* k1  = (float*)w; w += (size_t)NTOT * 64 * 4;
    float* v1  = (float*)w; w += (size_t)NTOT * 64 * 4;
    float* a1  = (float*)w; w += (size_t)NTOT * 16 * 4;

    k_csr<<<dim3(Bb), dim3(1024), 0, stream>>>(ei, agent, off, cpair, mark);
    k_mlpz<<<dim3(NTOT / 4), dim3(256), 0, stream>>>(
        nf, ea, ee, W1, b1, W2, b2, W3, b3, lg, lb,
        g1Wk, g1bk, g1Wv, g1bv,
        off, cpair, z, k1, v1);
    k_attn1<<<dim3(NTOT), dim3(256), 0, stream>>>(
        ea, k1, v1, z, mark,
        g1Wq, g1bq, g1We, g1Ws, g1bs,
        off, cpair, a1);
    k_g2<<<dim3(Bb), dim3(512), 0, stream>>>(
        ea, a1, agent, g2Wq, g2bq, g2Wk, g2bk, g2Wv, g2bv, g2We, g2Ws, g2bs,
        off, cpair, out);
}